// Round 1
// baseline (259.328 us; speedup 1.0000x reference)
//
#include <hip/hip_runtime.h>
#include <stdint.h>

#define NB 4
#define NH 16
#define DKH 64
#define DMODEL 1024
#define SEQ 1024
#define SCALE 0.125f
#define NEG_INF -1.0e9f

typedef __bf16 bf16_t;
typedef __bf16 bf16x8 __attribute__((ext_vector_type(8)));
typedef __bf16 bf16x4v __attribute__((ext_vector_type(4)));
typedef float f32x4 __attribute__((ext_vector_type(4)));

typedef const uint32_t __attribute__((address_space(1)))* gas_ptr;
typedef uint32_t __attribute__((address_space(3)))* las_ptr;

// async global->LDS, 16B per lane, dest = wave-uniform base + lane*16
__device__ __forceinline__ void gload_lds16(const void* g, void* l) {
  __builtin_amdgcn_global_load_lds((gas_ptr)g, (las_ptr)l, 16, 0, 0);
}

// ---------------- f32 -> bf16 conversion (select tensor by blockIdx.y) ----
__global__ void cvt_multi(const float* __restrict__ i0, const float* __restrict__ i1,
                          const float* __restrict__ i2, const float* __restrict__ i3,
                          const float* __restrict__ i4, const float* __restrict__ i5,
                          bf16_t* o0, bf16_t* o1, bf16_t* o2, bf16_t* o3, bf16_t* o4, bf16_t* o5,
                          int n) {
  const int t = blockIdx.y;
  const float* in = (t == 0) ? i0 : (t == 1) ? i1 : (t == 2) ? i2 : (t == 3) ? i3 : (t == 4) ? i4 : i5;
  bf16_t* out = (t == 0) ? o0 : (t == 1) ? o1 : (t == 2) ? o2 : (t == 3) ? o3 : (t == 4) ? o4 : o5;
  const int idx = (blockIdx.x * 256 + threadIdx.x) * 4;
  if (idx >= n) return;
  const float4 v = *(const float4*)(in + idx);
  bf16x4v p;
  p[0] = (bf16_t)v.x; p[1] = (bf16_t)v.y; p[2] = (bf16_t)v.z; p[3] = (bf16_t)v.w;
  *(bf16x4v*)(out + idx) = p;
}

// ---------------- GEMM: Y = A @ W^T + bias -------------------------------
// A [4096 x 1024] bf16 row-major, W [1024 x 1024] bf16 row-major (both K-contiguous).
// Tile 128x64, BK=64, 4 waves (2x2), wave tile 64x32 (4x2 frags of 16x16).
// MODE 0: bf16 out, head-split [B,H,L,DK]
// MODE 1: bf16 out, head-split transposed [B,H,DK,L]
// MODE 2: f32 out row-major [M, N]
template<int MODE>
__global__ void __launch_bounds__(256, 2)
gemm_bt(const bf16_t* __restrict__ A, const bf16_t* __restrict__ W,
        const float* __restrict__ bias, void* __restrict__ outp) {
  __shared__ bf16_t As[128 * 64];
  __shared__ bf16_t Bs[64 * 64];
  const int tid = threadIdx.x;
  const int lane = tid & 63;
  const int w = tid >> 6;
  const int wm = w >> 1, wn = w & 1;
  const int g = lane >> 4, c = lane & 15;
  const int bid = blockIdx.x;
  const int bm = bid >> 4, bn = bid & 15;     // 32 x 16 tiles
  const int m0 = bm * 128, n0 = bn * 64;
  const int lrow = lane >> 3, lcol = (lane & 7) * 8;

  f32x4 acc[4][2] = {};

  for (int kt = 0; kt < DMODEL; kt += 64) {
#pragma unroll
    for (int p = 0; p < 4; ++p) {
      const int row = w * 32 + p * 8;
      gload_lds16(A + (size_t)(m0 + row + lrow) * DMODEL + kt + lcol, &As[row * 64]);
    }
#pragma unroll
    for (int p = 0; p < 2; ++p) {
      const int row = w * 16 + p * 8;
      gload_lds16(W + (size_t)(n0 + row + lrow) * DMODEL + kt + lcol, &Bs[row * 64]);
    }
    __syncthreads();
    bf16x8 af[4][2], bfr[2][2];
#pragma unroll
    for (int i = 0; i < 4; ++i)
#pragma unroll
      for (int kk = 0; kk < 2; ++kk)
        af[i][kk] = *(const bf16x8*)&As[(wm * 64 + i * 16 + c) * 64 + kk * 32 + g * 8];
#pragma unroll
    for (int j = 0; j < 2; ++j)
#pragma unroll
      for (int kk = 0; kk < 2; ++kk)
        bfr[j][kk] = *(const bf16x8*)&Bs[(wn * 32 + j * 16 + c) * 64 + kk * 32 + g * 8];
#pragma unroll
    for (int i = 0; i < 4; ++i)
#pragma unroll
      for (int j = 0; j < 2; ++j) {
        acc[i][j] = __builtin_amdgcn_mfma_f32_16x16x32_bf16(af[i][0], bfr[j][0], acc[i][j], 0, 0, 0);
        acc[i][j] = __builtin_amdgcn_mfma_f32_16x16x32_bf16(af[i][1], bfr[j][1], acc[i][j], 0, 0, 0);
      }
    __syncthreads();
  }

  float bv2[2];
#pragma unroll
  for (int j = 0; j < 2; ++j) bv2[j] = bias[n0 + wn * 32 + j * 16 + c];

#pragma unroll
  for (int i = 0; i < 4; ++i) {
    const int mrow = m0 + wm * 64 + i * 16 + g * 4;   // C-layout: row = g*4 + r
    const int b_ = mrow >> 10, l_ = mrow & 1023;
#pragma unroll
    for (int j = 0; j < 2; ++j) {
      const int n = n0 + wn * 32 + j * 16 + c;        // C-layout: col = lane&15
      if (MODE == 2) {
        float* o = (float*)outp;
#pragma unroll
        for (int r = 0; r < 4; ++r)
          o[(size_t)(mrow + r) * DMODEL + n] = acc[i][j][r] + bv2[j];
      } else if (MODE == 0) {
        bf16_t* o = (bf16_t*)outp;
        const int h_ = n >> 6, dk_ = n & 63;
#pragma unroll
        for (int r = 0; r < 4; ++r)
          o[((size_t)(b_ * NH + h_) * SEQ + l_ + r) * DKH + dk_] =
              (bf16_t)(acc[i][j][r] + bv2[j]);
      } else { // MODE 1: transposed [B,H,DK,L]; 4 consecutive l -> packed 8B store
        bf16_t* o = (bf16_t*)outp;
        const int h_ = n >> 6, dk_ = n & 63;
        bf16x4v pk;
#pragma unroll
        for (int r = 0; r < 4; ++r) pk[r] = (bf16_t)(acc[i][j][r] + bv2[j]);
        *(bf16x4v*)&o[((size_t)(b_ * NH + h_) * DKH + dk_) * SEQ + l_] = pk;
      }
    }
  }
}

// ---------------- fused dual flash attention ------------------------------
// One KV-tile step for one attention (vis or rel). Kt [64 kv][64 d] LDS,
// Vt [64 d][64 kv] LDS (pre-transposed), Pw = per-wave [32][64] bf16 LDS.
__device__ __forceinline__ void attn_tile(
    const bf16_t* __restrict__ Kt, const bf16_t* __restrict__ Vt,
    bf16_t* __restrict__ Pw, const bf16x8 (&qf)[2][2], const int (&mk)[4],
    f32x4 (&m_s)[2], f32x4 (&l_s)[2], f32x4 (&o_s)[2][4], int lane) {
  const int g = lane >> 4, c = lane & 15;

  bf16x8 kfr[4][2];
#pragma unroll
  for (int f = 0; f < 4; ++f)
#pragma unroll
    for (int kk = 0; kk < 2; ++kk)
      kfr[f][kk] = *(const bf16x8*)&Kt[(f * 16 + c) * 64 + kk * 32 + g * 8];

  f32x4 s[2][4];
#pragma unroll
  for (int i = 0; i < 2; ++i)
#pragma unroll
    for (int f = 0; f < 4; ++f) {
      f32x4 a = {0.f, 0.f, 0.f, 0.f};
      a = __builtin_amdgcn_mfma_f32_16x16x32_bf16(qf[i][0], kfr[f][0], a, 0, 0, 0);
      a = __builtin_amdgcn_mfma_f32_16x16x32_bf16(qf[i][1], kfr[f][1], a, 0, 0, 0);
      s[i][f] = a;
    }

  // scale + mask (masked -> exactly NEG_INF, matching reference)
#pragma unroll
  for (int i = 0; i < 2; ++i)
#pragma unroll
    for (int f = 0; f < 4; ++f)
#pragma unroll
      for (int r = 0; r < 4; ++r)
        s[i][f][r] = (mk[f] == 0) ? NEG_INF : s[i][f][r] * SCALE;

#pragma unroll
  for (int i = 0; i < 2; ++i) {
    f32x4 tm = s[i][0];
#pragma unroll
    for (int f = 1; f < 4; ++f)
#pragma unroll
      for (int r = 0; r < 4; ++r) tm[r] = fmaxf(tm[r], s[i][f][r]);
#pragma unroll
    for (int d = 1; d < 16; d <<= 1)
#pragma unroll
      for (int r = 0; r < 4; ++r) tm[r] = fmaxf(tm[r], __shfl_xor(tm[r], d));

    f32x4 mnew, sf;
#pragma unroll
    for (int r = 0; r < 4; ++r) {
      mnew[r] = fmaxf(m_s[i][r], tm[r]);
      sf[r] = __expf(m_s[i][r] - mnew[r]);
    }
    m_s[i] = mnew;

    f32x4 psum = {0.f, 0.f, 0.f, 0.f};
#pragma unroll
    for (int f = 0; f < 4; ++f)
#pragma unroll
      for (int r = 0; r < 4; ++r) {
        const float p = __expf(s[i][f][r] - mnew[r]);
        s[i][f][r] = p;
        psum[r] += p;
      }
    // l kept as per-lane partial sum (sf is lane-uniform) -> one reduce at end
#pragma unroll
    for (int r = 0; r < 4; ++r) l_s[i][r] = l_s[i][r] * sf[r] + psum[r];
#pragma unroll
    for (int jd = 0; jd < 4; ++jd)
#pragma unroll
      for (int r = 0; r < 4; ++r) o_s[i][jd][r] *= sf[r];

    // P -> LDS (row-major [32 q][64 kv]) for MFMA A-fragment reads
#pragma unroll
    for (int f = 0; f < 4; ++f)
#pragma unroll
      for (int r = 0; r < 4; ++r)
        Pw[(i * 16 + g * 4 + r) * 64 + f * 16 + c] = (bf16_t)s[i][f][r];
  }

  // O += P @ V  (V pre-transposed: Vt[d][kv], k-contiguous B-operand)
  bf16x8 vfr[4][2];
#pragma unroll
  for (int jd = 0; jd < 4; ++jd)
#pragma unroll
    for (int kk = 0; kk < 2; ++kk)
      vfr[jd][kk] = *(const bf16x8*)&Vt[(jd * 16 + c) * 64 + kk * 32 + g * 8];
#pragma unroll
  for (int i = 0; i < 2; ++i) {
    bf16x8 pa[2];
#pragma unroll
    for (int kk = 0; kk < 2; ++kk)
      pa[kk] = *(const bf16x8*)&Pw[(i * 16 + c) * 64 + kk * 32 + g * 8];
#pragma unroll
    for (int jd = 0; jd < 4; ++jd) {
      o_s[i][jd] = __builtin_amdgcn_mfma_f32_16x16x32_bf16(pa[0], vfr[jd][0], o_s[i][jd], 0, 0, 0);
      o_s[i][jd] = __builtin_amdgcn_mfma_f32_16x16x32_bf16(pa[1], vfr[jd][1], o_s[i][jd], 0, 0, 0);
    }
  }
}

__global__ void __launch_bounds__(256, 2)
attn_kernel(const bf16_t* __restrict__ q, const bf16_t* __restrict__ k,
            const bf16_t* __restrict__ rk, const bf16_t* __restrict__ vT,
            const bf16_t* __restrict__ rvT, const int* __restrict__ mask,
            bf16_t* __restrict__ x) {
  __shared__ bf16_t Ks[64 * 64], RKs[64 * 64], Vs[64 * 64], RVs[64 * 64];
  __shared__ bf16_t Ps[4][32 * 64];

  const int tid = threadIdx.x;
  const int lane = tid & 63;
  const int w = tid >> 6;
  const int g = lane >> 4, c = lane & 15;
  const int bid = blockIdx.x;
  const int qt = bid & 7;
  const int bh = bid >> 3;
  const int b = bh >> 4, h = bh & 15;
  const int q0 = qt * 128;

  const bf16_t* qp = q + (size_t)bh * SEQ * DKH;
  const bf16_t* kp = k + (size_t)bh * SEQ * DKH;
  const bf16_t* rkp = rk + (size_t)bh * SEQ * DKH;
  const bf16_t* vp = vT + (size_t)bh * DKH * SEQ;
  const bf16_t* rvp = rvT + (size_t)bh * DKH * SEQ;
  const int* mp = mask + b * SEQ;
  const int lrow = lane >> 3, lcol = (lane & 7) * 8;

  // Q fragments in registers (wave owns 32 q-rows)
  bf16x8 qf[2][2];
#pragma unroll
  for (int i = 0; i < 2; ++i)
#pragma unroll
    for (int kk = 0; kk < 2; ++kk)
      qf[i][kk] = *(const bf16x8*)(qp + (size_t)(q0 + w * 32 + i * 16 + c) * DKH + kk * 32 + g * 8);

  f32x4 ov[2][4] = {}, orl[2][4] = {};
  f32x4 mv[2], lv[2], mr[2], lr[2];
#pragma unroll
  for (int i = 0; i < 2; ++i) {
    mv[i] = f32x4{NEG_INF, NEG_INF, NEG_INF, NEG_INF};
    mr[i] = mv[i];
    lv[i] = f32x4{0.f, 0.f, 0.f, 0.f};
    lr[i] = lv[i];
  }

  for (int kv0 = 0; kv0 < SEQ; kv0 += 64) {
#pragma unroll
    for (int p = 0; p < 2; ++p) {
      const int row = w * 16 + p * 8;
      gload_lds16(kp  + (size_t)(kv0 + row + lrow) * DKH + lcol, &Ks[row * 64]);
      gload_lds16(rkp + (size_t)(kv0 + row + lrow) * DKH + lcol, &RKs[row * 64]);
      gload_lds16(vp  + (size_t)(row + lrow) * SEQ + kv0 + lcol, &Vs[row * 64]);
      gload_lds16(rvp + (size_t)(row + lrow) * SEQ + kv0 + lcol, &RVs[row * 64]);
    }
    __syncthreads();

    int mk[4];
#pragma unroll
    for (int f = 0; f < 4; ++f) mk[f] = mp[kv0 + f * 16 + c];

    attn_tile(Ks, Vs, Ps[w], qf, mk, mv, lv, ov, lane);
    attn_tile(RKs, RVs, Ps[w], qf, mk, mr, lr, orl, lane);
    __syncthreads();
  }

  // reduce the per-lane partial softmax denominators across the 16 columns
#pragma unroll
  for (int i = 0; i < 2; ++i)
#pragma unroll
    for (int d = 1; d < 16; d <<= 1)
#pragma unroll
      for (int r = 0; r < 4; ++r) {
        lv[i][r] += __shfl_xor(lv[i][r], d);
        lr[i][r] += __shfl_xor(lr[i][r], d);
      }

  bf16_t* xb = x + (size_t)b * SEQ * DMODEL + (size_t)h * DKH;
#pragma unroll
  for (int i = 0; i < 2; ++i) {
    f32x4 rlv, rlr;
#pragma unroll
    for (int r = 0; r < 4; ++r) { rlv[r] = 1.0f / lv[i][r]; rlr[r] = 1.0f / lr[i][r]; }
#pragma unroll
    for (int jd = 0; jd < 4; ++jd)
#pragma unroll
      for (int r = 0; r < 4; ++r) {
        const int qrow = q0 + w * 32 + i * 16 + g * 4 + r;
        const float val = ov[i][jd][r] * rlv[r] + orl[i][jd][r] * rlr[r];
        xb[(size_t)qrow * DMODEL + jd * 16 + c] = (bf16_t)val;
      }
  }
}

// ---------------- host launch ---------------------------------------------
extern "C" void kernel_launch(void* const* d_in, const int* in_sizes, int n_in,
                              void* d_out, int out_size, void* d_ws, size_t ws_size,
                              hipStream_t stream) {
  (void)in_sizes; (void)n_in; (void)out_size; (void)ws_size;
  const float* query = (const float*)d_in[0];
  const float* key_  = (const float*)d_in[1];
  const float* value = (const float*)d_in[2];
  const float* weak  = (const float*)d_in[3];
  const int*   mask  = (const int*)d_in[4];
  const float* Wq  = (const float*)d_in[5];  const float* bq  = (const float*)d_in[6];
  const float* Wk  = (const float*)d_in[7];  const float* bk  = (const float*)d_in[8];
  const float* Wv  = (const float*)d_in[9];  const float* bv  = (const float*)d_in[10];
  const float* Wrk = (const float*)d_in[11]; const float* brk = (const float*)d_in[12];
  const float* Wrv = (const float*)d_in[13]; const float* brv = (const float*)d_in[14];
  const float* Wo  = (const float*)d_in[15]; const float* bo  = (const float*)d_in[16];

  char* ws = (char*)d_ws;
  size_t off = 0;
  auto alloc = [&](size_t bytes) {
    void* p = ws + off;
    off += (bytes + 255) & ~(size_t)255;
    return p;
  };
  const size_t SZ_X = (size_t)NB * SEQ * DMODEL * sizeof(bf16_t); // 8 MB
  const size_t SZ_W = (size_t)DMODEL * DMODEL * sizeof(bf16_t);   // 2 MB

  bf16_t* Xq = (bf16_t*)alloc(SZ_X);
  bf16_t* Xk = (bf16_t*)alloc(SZ_X);
  bf16_t* Xv = (bf16_t*)alloc(SZ_X);
  bf16_t* Xr = (bf16_t*)alloc(SZ_X);
  bf16_t* Wqb  = (bf16_t*)alloc(SZ_W);
  bf16_t* Wkb  = (bf16_t*)alloc(SZ_W);
  bf16_t* Wvb  = (bf16_t*)alloc(SZ_W);
  bf16_t* Wrkb = (bf16_t*)alloc(SZ_W);
  bf16_t* Wrvb = (bf16_t*)alloc(SZ_W);
  bf16_t* Wob  = (bf16_t*)alloc(SZ_W);
  bf16_t* qh   = (bf16_t*)alloc(SZ_X);
  bf16_t* kh   = (bf16_t*)alloc(SZ_X);
  bf16_t* rkh  = (bf16_t*)alloc(SZ_X);
  bf16_t* vTh  = (bf16_t*)alloc(SZ_X);
  bf16_t* rvTh = (bf16_t*)alloc(SZ_X);
  bf16_t* xh   = (bf16_t*)alloc(SZ_X);

  // f32 -> bf16
  cvt_multi<<<dim3(4096, 4), 256, 0, stream>>>(query, key_, value, weak, nullptr, nullptr,
                                               Xq, Xk, Xv, Xr, nullptr, nullptr,
                                               NB * SEQ * DMODEL);
  cvt_multi<<<dim3(1024, 6), 256, 0, stream>>>(Wq, Wk, Wv, Wrk, Wrv, Wo,
                                               Wqb, Wkb, Wvb, Wrkb, Wrvb, Wob,
                                               DMODEL * DMODEL);

  // projections (512 blocks = 32 m-tiles x 16 n-tiles)
  gemm_bt<0><<<dim3(512), 256, 0, stream>>>(Xq, Wqb, bq, qh);
  gemm_bt<0><<<dim3(512), 256, 0, stream>>>(Xk, Wkb, bk, kh);
  gemm_bt<0><<<dim3(512), 256, 0, stream>>>(Xr, Wrkb, brk, rkh);
  gemm_bt<1><<<dim3(512), 256, 0, stream>>>(Xv, Wvb, bv, vTh);
  gemm_bt<1><<<dim3(512), 256, 0, stream>>>(Xr, Wrvb, brv, rvTh);

  // fused dual attention: 4 b * 16 h * 8 q-tiles = 512 blocks
  attn_kernel<<<dim3(512), 256, 0, stream>>>(qh, kh, rkh, vTh, rvTh, mask, xh);

  // output projection -> f32 d_out
  gemm_bt<2><<<dim3(512), 256, 0, stream>>>(xh, Wob, bo, d_out);
}

// Round 2
// 228.332 us; speedup vs baseline: 1.1357x; 1.1357x over previous
//
#include <hip/hip_runtime.h>
#include <stdint.h>

#define NB 4
#define NH 16
#define DKH 64
#define DMODEL 1024
#define SEQ 1024
#define SCALE 0.125f
#define NEG_INF -1.0e9f

typedef __bf16 bf16_t;
typedef __bf16 bf16x8 __attribute__((ext_vector_type(8)));
typedef __bf16 bf16x4v __attribute__((ext_vector_type(4)));
typedef float f32x4 __attribute__((ext_vector_type(4)));

typedef const uint32_t __attribute__((address_space(1)))* gas_ptr;
typedef uint32_t __attribute__((address_space(3)))* las_ptr;

// async global->LDS, 16B per lane, dest = wave-uniform base + lane*16
__device__ __forceinline__ void gload_lds16(const void* g, void* l) {
  __builtin_amdgcn_global_load_lds((gas_ptr)g, (las_ptr)l, 16, 0, 0);
}

// T2 XOR swizzle for [R][64] bf16 tiles (128B rows): element col ^= (row&7)<<3.
// Staging keeps LDS dest linear and pre-swizzles the GLOBAL source column
// (valid because every staged 8-row chunk starts at row%8==0); all LDS reads
// and reg->LDS writes apply the same XOR. (rule #21: both-sides involution)
__device__ __forceinline__ int swz(int row, int col) {
  return col ^ ((row & 7) << 3);
}

// ---------------- f32 -> bf16 conversion (select tensor by blockIdx.y) ----
__global__ void cvt_multi(const float* __restrict__ i0, const float* __restrict__ i1,
                          const float* __restrict__ i2, const float* __restrict__ i3,
                          const float* __restrict__ i4, const float* __restrict__ i5,
                          bf16_t* o0, bf16_t* o1, bf16_t* o2, bf16_t* o3, bf16_t* o4, bf16_t* o5,
                          int n) {
  const int t = blockIdx.y;
  const float* in = (t == 0) ? i0 : (t == 1) ? i1 : (t == 2) ? i2 : (t == 3) ? i3 : (t == 4) ? i4 : i5;
  bf16_t* out = (t == 0) ? o0 : (t == 1) ? o1 : (t == 2) ? o2 : (t == 3) ? o3 : (t == 4) ? o4 : o5;
  const int idx = (blockIdx.x * 256 + threadIdx.x) * 4;
  if (idx >= n) return;
  const float4 v = *(const float4*)(in + idx);
  bf16x4v p;
  p[0] = (bf16_t)v.x; p[1] = (bf16_t)v.y; p[2] = (bf16_t)v.z; p[3] = (bf16_t)v.w;
  *(bf16x4v*)(out + idx) = p;
}

// ---------------- GEMM: Y = A @ W^T + bias -------------------------------
// A [4096 x 1024] bf16 row-major, W [1024 x 1024] bf16 row-major (both K-contiguous).
// Tile 128x64, BK=64, 4 waves (2x2), wave tile 64x32 (4x2 frags of 16x16).
// MODE 0: bf16 out, head-split [B,H,L,DK]
// MODE 1: bf16 out, head-split transposed [B,H,DK,L]
// MODE 2: f32 out row-major [M, N]
template<int MODE>
__global__ void __launch_bounds__(256, 2)
gemm_bt(const bf16_t* __restrict__ A, const bf16_t* __restrict__ W,
        const float* __restrict__ bias, void* __restrict__ outp) {
  __shared__ bf16_t As[128 * 64];
  __shared__ bf16_t Bs[64 * 64];
  const int tid = threadIdx.x;
  const int lane = tid & 63;
  const int w = tid >> 6;
  const int wm = w >> 1, wn = w & 1;
  const int g = lane >> 4, c = lane & 15;
  const int bid = blockIdx.x;
  const int bm = bid >> 4, bn = bid & 15;     // 32 x 16 tiles
  const int m0 = bm * 128, n0 = bn * 64;
  const int lrow = lane >> 3;
  const int lcol = ((lane & 7) * 8) ^ ((lane >> 3) << 3);  // pre-swizzled source col
  const int sc = (c & 7) << 3;                             // read-side XOR

  f32x4 acc[4][2] = {};

  for (int kt = 0; kt < DMODEL; kt += 64) {
#pragma unroll
    for (int p = 0; p < 4; ++p) {
      const int row = w * 32 + p * 8;
      gload_lds16(A + (size_t)(m0 + row + lrow) * DMODEL + kt + lcol, &As[row * 64]);
    }
#pragma unroll
    for (int p = 0; p < 2; ++p) {
      const int row = w * 16 + p * 8;
      gload_lds16(W + (size_t)(n0 + row + lrow) * DMODEL + kt + lcol, &Bs[row * 64]);
    }
    __syncthreads();
    bf16x8 af[4][2], bfr[2][2];
#pragma unroll
    for (int i = 0; i < 4; ++i)
#pragma unroll
      for (int kk = 0; kk < 2; ++kk)
        af[i][kk] = *(const bf16x8*)&As[(wm * 64 + i * 16 + c) * 64 + ((kk * 32 + g * 8) ^ sc)];
#pragma unroll
    for (int j = 0; j < 2; ++j)
#pragma unroll
      for (int kk = 0; kk < 2; ++kk)
        bfr[j][kk] = *(const bf16x8*)&Bs[(wn * 32 + j * 16 + c) * 64 + ((kk * 32 + g * 8) ^ sc)];
#pragma unroll
    for (int i = 0; i < 4; ++i)
#pragma unroll
      for (int j = 0; j < 2; ++j) {
        acc[i][j] = __builtin_amdgcn_mfma_f32_16x16x32_bf16(af[i][0], bfr[j][0], acc[i][j], 0, 0, 0);
        acc[i][j] = __builtin_amdgcn_mfma_f32_16x16x32_bf16(af[i][1], bfr[j][1], acc[i][j], 0, 0, 0);
      }
    __syncthreads();
  }

  float bv2[2];
#pragma unroll
  for (int j = 0; j < 2; ++j) bv2[j] = bias[n0 + wn * 32 + j * 16 + c];

#pragma unroll
  for (int i = 0; i < 4; ++i) {
    const int mrow = m0 + wm * 64 + i * 16 + g * 4;   // C-layout: row = g*4 + r
    const int b_ = mrow >> 10, l_ = mrow & 1023;
#pragma unroll
    for (int j = 0; j < 2; ++j) {
      const int n = n0 + wn * 32 + j * 16 + c;        // C-layout: col = lane&15
      if (MODE == 2) {
        float* o = (float*)outp;
#pragma unroll
        for (int r = 0; r < 4; ++r)
          o[(size_t)(mrow + r) * DMODEL + n] = acc[i][j][r] + bv2[j];
      } else if (MODE == 0) {
        bf16_t* o = (bf16_t*)outp;
        const int h_ = n >> 6, dk_ = n & 63;
#pragma unroll
        for (int r = 0; r < 4; ++r)
          o[((size_t)(b_ * NH + h_) * SEQ + l_ + r) * DKH + dk_] =
              (bf16_t)(acc[i][j][r] + bv2[j]);
      } else { // MODE 1: transposed [B,H,DK,L]; 4 consecutive l -> packed 8B store
        bf16_t* o = (bf16_t*)outp;
        const int h_ = n >> 6, dk_ = n & 63;
        bf16x4v pk;
#pragma unroll
        for (int r = 0; r < 4; ++r) pk[r] = (bf16_t)(acc[i][j][r] + bv2[j]);
        *(bf16x4v*)&o[((size_t)(b_ * NH + h_) * DKH + dk_) * SEQ + l_] = pk;
      }
    }
  }
}

// ---------------- fused dual flash attention ------------------------------
// One KV-tile step for one attention (vis or rel). Kt [64 kv][64 d] LDS,
// Vt [64 d][64 kv] LDS (pre-transposed), Pw = per-wave [32][64] bf16 LDS.
// All tiles XOR-swizzled (T2).
__device__ __forceinline__ void attn_tile(
    const bf16_t* __restrict__ Kt, const bf16_t* __restrict__ Vt,
    bf16_t* __restrict__ Pw, const bf16x8 (&qf)[2][2], const int (&mk)[4],
    f32x4 (&m_s)[2], f32x4 (&l_s)[2], f32x4 (&o_s)[2][4], int lane) {
  const int g = lane >> 4, c = lane & 15;
  const int sc = (c & 7) << 3;

  bf16x8 kfr[4][2];
#pragma unroll
  for (int f = 0; f < 4; ++f)
#pragma unroll
    for (int kk = 0; kk < 2; ++kk)
      kfr[f][kk] = *(const bf16x8*)&Kt[(f * 16 + c) * 64 + ((kk * 32 + g * 8) ^ sc)];

  f32x4 s[2][4];
#pragma unroll
  for (int i = 0; i < 2; ++i)
#pragma unroll
    for (int f = 0; f < 4; ++f) {
      f32x4 a = {0.f, 0.f, 0.f, 0.f};
      a = __builtin_amdgcn_mfma_f32_16x16x32_bf16(qf[i][0], kfr[f][0], a, 0, 0, 0);
      a = __builtin_amdgcn_mfma_f32_16x16x32_bf16(qf[i][1], kfr[f][1], a, 0, 0, 0);
      s[i][f] = a;
    }

  // scale + mask (masked -> exactly NEG_INF, matching reference)
#pragma unroll
  for (int i = 0; i < 2; ++i)
#pragma unroll
    for (int f = 0; f < 4; ++f)
#pragma unroll
      for (int r = 0; r < 4; ++r)
        s[i][f][r] = (mk[f] == 0) ? NEG_INF : s[i][f][r] * SCALE;

#pragma unroll
  for (int i = 0; i < 2; ++i) {
    f32x4 tm = s[i][0];
#pragma unroll
    for (int f = 1; f < 4; ++f)
#pragma unroll
      for (int r = 0; r < 4; ++r) tm[r] = fmaxf(tm[r], s[i][f][r]);
#pragma unroll
    for (int d = 1; d < 16; d <<= 1)
#pragma unroll
      for (int r = 0; r < 4; ++r) tm[r] = fmaxf(tm[r], __shfl_xor(tm[r], d));

    f32x4 mnew, sf;
#pragma unroll
    for (int r = 0; r < 4; ++r) {
      mnew[r] = fmaxf(m_s[i][r], tm[r]);
      sf[r] = __expf(m_s[i][r] - mnew[r]);
    }
    m_s[i] = mnew;

    f32x4 psum = {0.f, 0.f, 0.f, 0.f};
#pragma unroll
    for (int f = 0; f < 4; ++f)
#pragma unroll
      for (int r = 0; r < 4; ++r) {
        const float p = __expf(s[i][f][r] - mnew[r]);
        s[i][f][r] = p;
        psum[r] += p;
      }
    // l kept as per-lane partial sum (sf is lane-uniform) -> one reduce at end
#pragma unroll
    for (int r = 0; r < 4; ++r) l_s[i][r] = l_s[i][r] * sf[r] + psum[r];
#pragma unroll
    for (int jd = 0; jd < 4; ++jd)
#pragma unroll
      for (int r = 0; r < 4; ++r) o_s[i][jd][r] *= sf[r];

    // P -> LDS (row-major [32 q][64 kv], swizzled) for MFMA A-fragment reads
#pragma unroll
    for (int f = 0; f < 4; ++f)
#pragma unroll
      for (int r = 0; r < 4; ++r)
        Pw[(i * 16 + g * 4 + r) * 64 + ((f * 16 + c) ^ (((g * 4 + r) & 7) << 3))] =
            (bf16_t)s[i][f][r];
  }

  // O += P @ V  (V pre-transposed: Vt[d][kv], k-contiguous B-operand)
  bf16x8 vfr[4][2];
#pragma unroll
  for (int jd = 0; jd < 4; ++jd)
#pragma unroll
    for (int kk = 0; kk < 2; ++kk)
      vfr[jd][kk] = *(const bf16x8*)&Vt[(jd * 16 + c) * 64 + ((kk * 32 + g * 8) ^ sc)];
#pragma unroll
  for (int i = 0; i < 2; ++i) {
    bf16x8 pa[2];
#pragma unroll
    for (int kk = 0; kk < 2; ++kk)
      pa[kk] = *(const bf16x8*)&Pw[(i * 16 + c) * 64 + ((kk * 32 + g * 8) ^ sc)];
#pragma unroll
    for (int jd = 0; jd < 4; ++jd) {
      o_s[i][jd] = __builtin_amdgcn_mfma_f32_16x16x32_bf16(pa[0], vfr[jd][0], o_s[i][jd], 0, 0, 0);
      o_s[i][jd] = __builtin_amdgcn_mfma_f32_16x16x32_bf16(pa[1], vfr[jd][1], o_s[i][jd], 0, 0, 0);
    }
  }
}

__global__ void __launch_bounds__(256, 2)
attn_kernel(const bf16_t* __restrict__ q, const bf16_t* __restrict__ k,
            const bf16_t* __restrict__ rk, const bf16_t* __restrict__ vT,
            const bf16_t* __restrict__ rvT, const int* __restrict__ mask,
            bf16_t* __restrict__ x) {
  __shared__ bf16_t Ks[64 * 64], RKs[64 * 64], Vs[64 * 64], RVs[64 * 64];
  __shared__ bf16_t Ps[4][32 * 64];

  const int tid = threadIdx.x;
  const int lane = tid & 63;
  const int w = tid >> 6;
  const int g = lane >> 4, c = lane & 15;
  const int bid = blockIdx.x;
  const int qt = bid & 7;
  const int bh = bid >> 3;
  const int b = bh >> 4, h = bh & 15;
  const int q0 = qt * 128;

  const bf16_t* qp = q + (size_t)bh * SEQ * DKH;
  const bf16_t* kp = k + (size_t)bh * SEQ * DKH;
  const bf16_t* rkp = rk + (size_t)bh * SEQ * DKH;
  const bf16_t* vp = vT + (size_t)bh * DKH * SEQ;
  const bf16_t* rvp = rvT + (size_t)bh * DKH * SEQ;
  const int* mp = mask + b * SEQ;
  const int lrow = lane >> 3;
  const int lcol = ((lane & 7) * 8) ^ ((lane >> 3) << 3);  // pre-swizzled source col

  // Q fragments in registers (wave owns 32 q-rows)
  bf16x8 qf[2][2];
#pragma unroll
  for (int i = 0; i < 2; ++i)
#pragma unroll
    for (int kk = 0; kk < 2; ++kk)
      qf[i][kk] = *(const bf16x8*)(qp + (size_t)(q0 + w * 32 + i * 16 + c) * DKH + kk * 32 + g * 8);

  f32x4 ov[2][4] = {}, orl[2][4] = {};
  f32x4 mv[2], lv[2], mr[2], lr[2];
#pragma unroll
  for (int i = 0; i < 2; ++i) {
    mv[i] = f32x4{NEG_INF, NEG_INF, NEG_INF, NEG_INF};
    mr[i] = mv[i];
    lv[i] = f32x4{0.f, 0.f, 0.f, 0.f};
    lr[i] = lv[i];
  }

  for (int kv0 = 0; kv0 < SEQ; kv0 += 64) {
#pragma unroll
    for (int p = 0; p < 2; ++p) {
      const int row = w * 16 + p * 8;
      gload_lds16(kp  + (size_t)(kv0 + row + lrow) * DKH + lcol, &Ks[row * 64]);
      gload_lds16(rkp + (size_t)(kv0 + row + lrow) * DKH + lcol, &RKs[row * 64]);
      gload_lds16(vp  + (size_t)(row + lrow) * SEQ + kv0 + lcol, &Vs[row * 64]);
      gload_lds16(rvp + (size_t)(row + lrow) * SEQ + kv0 + lcol, &RVs[row * 64]);
    }
    __syncthreads();

    int mk[4];
#pragma unroll
    for (int f = 0; f < 4; ++f) mk[f] = mp[kv0 + f * 16 + c];

    attn_tile(Ks, Vs, Ps[w], qf, mk, mv, lv, ov, lane);
    attn_tile(RKs, RVs, Ps[w], qf, mk, mr, lr, orl, lane);
    __syncthreads();
  }

  // reduce the per-lane partial softmax denominators across the 16 columns
#pragma unroll
  for (int i = 0; i < 2; ++i)
#pragma unroll
    for (int d = 1; d < 16; d <<= 1)
#pragma unroll
      for (int r = 0; r < 4; ++r) {
        lv[i][r] += __shfl_xor(lv[i][r], d);
        lr[i][r] += __shfl_xor(lr[i][r], d);
      }

  bf16_t* xb = x + (size_t)b * SEQ * DMODEL + (size_t)h * DKH;
#pragma unroll
  for (int i = 0; i < 2; ++i) {
    f32x4 rlv, rlr;
#pragma unroll
    for (int r = 0; r < 4; ++r) { rlv[r] = 1.0f / lv[i][r]; rlr[r] = 1.0f / lr[i][r]; }
#pragma unroll
    for (int jd = 0; jd < 4; ++jd)
#pragma unroll
      for (int r = 0; r < 4; ++r) {
        const int qrow = q0 + w * 32 + i * 16 + g * 4 + r;
        const float val = ov[i][jd][r] * rlv[r] + orl[i][jd][r] * rlr[r];
        xb[(size_t)qrow * DMODEL + jd * 16 + c] = (bf16_t)val;
      }
  }
}

// ---------------- host launch ---------------------------------------------
extern "C" void kernel_launch(void* const* d_in, const int* in_sizes, int n_in,
                              void* d_out, int out_size, void* d_ws, size_t ws_size,
                              hipStream_t stream) {
  (void)in_sizes; (void)n_in; (void)out_size; (void)ws_size;
  const float* query = (const float*)d_in[0];
  const float* key_  = (const float*)d_in[1];
  const float* value = (const float*)d_in[2];
  const float* weak  = (const float*)d_in[3];
  const int*   mask  = (const int*)d_in[4];
  const float* Wq  = (const float*)d_in[5];  const float* bq  = (const float*)d_in[6];
  const float* Wk  = (const float*)d_in[7];  const float* bk  = (const float*)d_in[8];
  const float* Wv  = (const float*)d_in[9];  const float* bv  = (const float*)d_in[10];
  const float* Wrk = (const float*)d_in[11]; const float* brk = (const float*)d_in[12];
  const float* Wrv = (const float*)d_in[13]; const float* brv = (const float*)d_in[14];
  const float* Wo  = (const float*)d_in[15]; const float* bo  = (const float*)d_in[16];

  char* ws = (char*)d_ws;
  size_t off = 0;
  auto alloc = [&](size_t bytes) {
    void* p = ws + off;
    off += (bytes + 255) & ~(size_t)255;
    return p;
  };
  const size_t SZ_X = (size_t)NB * SEQ * DMODEL * sizeof(bf16_t); // 8 MB
  const size_t SZ_W = (size_t)DMODEL * DMODEL * sizeof(bf16_t);   // 2 MB

  bf16_t* Xq = (bf16_t*)alloc(SZ_X);
  bf16_t* Xk = (bf16_t*)alloc(SZ_X);
  bf16_t* Xv = (bf16_t*)alloc(SZ_X);
  bf16_t* Xr = (bf16_t*)alloc(SZ_X);
  bf16_t* Wqb  = (bf16_t*)alloc(SZ_W);
  bf16_t* Wkb  = (bf16_t*)alloc(SZ_W);
  bf16_t* Wvb  = (bf16_t*)alloc(SZ_W);
  bf16_t* Wrkb = (bf16_t*)alloc(SZ_W);
  bf16_t* Wrvb = (bf16_t*)alloc(SZ_W);
  bf16_t* Wob  = (bf16_t*)alloc(SZ_W);
  bf16_t* qh   = (bf16_t*)alloc(SZ_X);
  bf16_t* kh   = (bf16_t*)alloc(SZ_X);
  bf16_t* rkh  = (bf16_t*)alloc(SZ_X);
  bf16_t* vTh  = (bf16_t*)alloc(SZ_X);
  bf16_t* rvTh = (bf16_t*)alloc(SZ_X);
  bf16_t* xh   = (bf16_t*)alloc(SZ_X);

  // f32 -> bf16
  cvt_multi<<<dim3(4096, 4), 256, 0, stream>>>(query, key_, value, weak, nullptr, nullptr,
                                               Xq, Xk, Xv, Xr, nullptr, nullptr,
                                               NB * SEQ * DMODEL);
  cvt_multi<<<dim3(1024, 6), 256, 0, stream>>>(Wq, Wk, Wv, Wrk, Wrv, Wo,
                                               Wqb, Wkb, Wvb, Wrkb, Wrvb, Wob,
                                               DMODEL * DMODEL);

  // projections (512 blocks = 32 m-tiles x 16 n-tiles)
  gemm_bt<0><<<dim3(512), 256, 0, stream>>>(Xq, Wqb, bq, qh);
  gemm_bt<0><<<dim3(512), 256, 0, stream>>>(Xk, Wkb, bk, kh);
  gemm_bt<0><<<dim3(512), 256, 0, stream>>>(Xr, Wrkb, brk, rkh);
  gemm_bt<1><<<dim3(512), 256, 0, stream>>>(Xv, Wvb, bv, vTh);
  gemm_bt<1><<<dim3(512), 256, 0, stream>>>(Xr, Wrvb, brv, rvTh);

  // fused dual attention: 4 b * 16 h * 8 q-tiles = 512 blocks
  attn_kernel<<<dim3(512), 256, 0, stream>>>(qh, kh, rkh, vTh, rvTh, mask, xh);

  // output projection -> f32 d_out
  gemm_bt<2><<<dim3(512), 256, 0, stream>>>(xh, Wob, bo, d_out);
}